// Round 3
// baseline (257.836 us; speedup 1.0000x reference)
//
#include <hip/hip_runtime.h>

// Flash attention forward, fp32 in/out, fp16 MFMA compute.
// B=8, SQ=SK=4096, D=64. scores = (Q/x5) K^T ; softmax ; O = P V.
// R3: BQ=64 (each of 4 waves owns ONE 16-row M-tile) -> grid = 8*64 = 512
// blocks = 2 blocks/CU co-resident. cvt_pkrtz via __fp16 vector type (fixes R2
// compile error: the builtin returns __fp16x2, not _Float16x2).

typedef _Float16 f16x8 __attribute__((ext_vector_type(8)));
typedef __fp16   h16x2 __attribute__((ext_vector_type(2)));   // cvt_pkrtz return type
typedef float    f32x4 __attribute__((ext_vector_type(4)));

constexpr int kB  = 8;
constexpr int kSQ = 4096;
constexpr int kSK = 4096;
constexpr int kD  = 64;
constexpr int BQ  = 64;         // Q rows per block (4 waves x 16 rows)
constexpr int BK  = 64;         // keys per iteration
constexpr int LDK = kD + 8;     // 72
constexpr int LDV = BK + 8;     // 72
constexpr int LDP = BK + 8;     // 72

__global__ __launch_bounds__(256, 2)
void fattn_kernel(const float* __restrict__ Qg,
                  const float* __restrict__ Kg,
                  const float* __restrict__ Vg,
                  const float* __restrict__ sdiv,
                  float* __restrict__ Og)
{
    __shared__ __align__(16) _Float16 sK[BK][LDK];     // [key][feat]
    __shared__ __align__(16) _Float16 sV[kD][LDV];     // [feat][key] (V transposed)
    __shared__ __align__(16) _Float16 sP[4][16][LDP];  // per-wave P buffer

    const int tid  = threadIdx.x;
    const int w    = tid >> 6;
    const int lane = tid & 63;
    const int l16  = lane & 15;
    const int quad = lane >> 4;

    const int b  = blockIdx.y;
    const int qb = blockIdx.x * BQ;

    const float inv_scale = 1.0f / sdiv[0];

    const float* Qb = Qg + ((size_t)b * kSQ + qb) * kD;
    const float* Kb = Kg + (size_t)b * kSK * kD;
    const float* Vb = Vg + (size_t)b * kSK * kD;

    // ---- Q fragments (one 16-row M-tile per wave), registers for whole kernel
    // A-layout: m = l16, k = ks*32 + quad*8 + j
    f16x8 qf[2];
    {
        const float* qrow = Qb + (size_t)(w * 16 + l16) * kD;
#pragma unroll
        for (int ks = 0; ks < 2; ++ks) {
            const float4 a = *(const float4*)(qrow + ks * 32 + quad * 8);
            const float4 c = *(const float4*)(qrow + ks * 32 + quad * 8 + 4);
            h16x2 p0 = __builtin_amdgcn_cvt_pkrtz(a.x * inv_scale, a.y * inv_scale);
            h16x2 p1 = __builtin_amdgcn_cvt_pkrtz(a.z * inv_scale, a.w * inv_scale);
            h16x2 p2 = __builtin_amdgcn_cvt_pkrtz(c.x * inv_scale, c.y * inv_scale);
            h16x2 p3 = __builtin_amdgcn_cvt_pkrtz(c.z * inv_scale, c.w * inv_scale);
            f16x8 f;
            f[0] = (_Float16)p0[0]; f[1] = (_Float16)p0[1];
            f[2] = (_Float16)p1[0]; f[3] = (_Float16)p1[1];
            f[4] = (_Float16)p2[0]; f[5] = (_Float16)p2[1];
            f[6] = (_Float16)p3[0]; f[7] = (_Float16)p3[1];
            qf[ks] = f;
        }
    }

    // ---- online-softmax state ----
    f32x4 o[4];                 // O accumulator, C-layout, 4 d-tiles of 16
    float m_i[4], l_i[4];
#pragma unroll
    for (int r = 0; r < 4; ++r) { m_i[r] = -1e30f; l_i[r] = 0.0f; }
#pragma unroll
    for (int dt = 0; dt < 4; ++dt)
#pragma unroll
        for (int r = 0; r < 4; ++r) o[dt][r] = 0.0f;

    const int nIter = kSK / BK;
    for (int kt = 0; kt < nIter; ++kt) {
        __syncthreads();
        // ---- stage K tile and V tile (transposed) into LDS, fp32 -> fp16 ----
        const float* Kt = Kb + (size_t)kt * BK * kD;
        const float* Vt = Vb + (size_t)kt * BK * kD;
#pragma unroll
        for (int i = 0; i < 4; ++i) {
            const int idx = i * 256 + tid;
            const int row = idx >> 4;          // key row 0..63
            const int cb  = (idx & 15) * 4;    // feature col 0..60
            const float4 kv = *(const float4*)(Kt + row * kD + cb);
            h16x2* kd = (h16x2*)&sK[row][cb];
            kd[0] = __builtin_amdgcn_cvt_pkrtz(kv.x, kv.y);
            kd[1] = __builtin_amdgcn_cvt_pkrtz(kv.z, kv.w);
            const float4 vv = *(const float4*)(Vt + row * kD + cb);
            sV[cb + 0][row] = (_Float16)vv.x;
            sV[cb + 1][row] = (_Float16)vv.y;
            sV[cb + 2][row] = (_Float16)vv.z;
            sV[cb + 3][row] = (_Float16)vv.w;
        }
        __syncthreads();

        // ---- S = Q K^T  (per wave: 16 rows x 64 keys) ----
        // B-layout for K: n = key = nt*16 + l16, k = feat = ks*32 + quad*8 + j
        f16x8 kf[4][2];
#pragma unroll
        for (int nt = 0; nt < 4; ++nt)
#pragma unroll
            for (int ks = 0; ks < 2; ++ks)
                kf[nt][ks] = *(const f16x8*)&sK[nt * 16 + l16][ks * 32 + quad * 8];

        f32x4 s[4];
#pragma unroll
        for (int nt = 0; nt < 4; ++nt) {
            f32x4 acc;
#pragma unroll
            for (int r = 0; r < 4; ++r) acc[r] = 0.0f;
            acc = __builtin_amdgcn_mfma_f32_16x16x32_f16(qf[0], kf[nt][0], acc, 0, 0, 0);
            acc = __builtin_amdgcn_mfma_f32_16x16x32_f16(qf[1], kf[nt][1], acc, 0, 0, 0);
            s[nt] = acc;
        }

        // ---- online softmax (C-layout: col = l16, row = quad*4 + r) ----
        {
            float rm[4], rs[4], alpha[4];
#pragma unroll
            for (int r = 0; r < 4; ++r) {
                float v = s[0][r];
                v = fmaxf(v, s[1][r]);
                v = fmaxf(v, s[2][r]);
                v = fmaxf(v, s[3][r]);
                rm[r] = v;
            }
#pragma unroll
            for (int off = 1; off < 16; off <<= 1)
#pragma unroll
                for (int r = 0; r < 4; ++r)
                    rm[r] = fmaxf(rm[r], __shfl_xor(rm[r], off, 64));
#pragma unroll
            for (int r = 0; r < 4; ++r) {
                const float mnew = fmaxf(m_i[r], rm[r]);
                alpha[r] = __expf(m_i[r] - mnew);
                m_i[r] = mnew;
            }
#pragma unroll
            for (int r = 0; r < 4; ++r) {
                float sum = 0.0f;
#pragma unroll
                for (int nt = 0; nt < 4; ++nt) {
                    const float p = __expf(s[nt][r] - m_i[r]);
                    s[nt][r] = p;
                    sum += p;
                }
                rs[r] = sum;
            }
#pragma unroll
            for (int off = 1; off < 16; off <<= 1)
#pragma unroll
                for (int r = 0; r < 4; ++r)
                    rs[r] += __shfl_xor(rs[r], off, 64);
#pragma unroll
            for (int r = 0; r < 4; ++r)
                l_i[r] = l_i[r] * alpha[r] + rs[r];
#pragma unroll
            for (int dt = 0; dt < 4; ++dt)
#pragma unroll
                for (int r = 0; r < 4; ++r)
                    o[dt][r] *= alpha[r];
            // P: C-layout -> LDS (wave-private, no barrier needed)
#pragma unroll
            for (int nt = 0; nt < 4; ++nt)
#pragma unroll
                for (int r = 0; r < 4; ++r)
                    sP[w][quad * 4 + r][nt * 16 + l16] = (_Float16)s[nt][r];
        }

        // ---- O += P V ----
        // B-layout for V: n = feat = dt*16 + l16, k = key = ks*32 + quad*8 + j
        f16x8 vf[4][2];
#pragma unroll
        for (int dt = 0; dt < 4; ++dt)
#pragma unroll
            for (int ks = 0; ks < 2; ++ks)
                vf[dt][ks] = *(const f16x8*)&sV[dt * 16 + l16][ks * 32 + quad * 8];
        f16x8 pf[2];
#pragma unroll
        for (int ks = 0; ks < 2; ++ks)
            pf[ks] = *(const f16x8*)&sP[w][l16][ks * 32 + quad * 8];
#pragma unroll
        for (int dt = 0; dt < 4; ++dt) {
            o[dt] = __builtin_amdgcn_mfma_f32_16x16x32_f16(pf[0], vf[dt][0], o[dt], 0, 0, 0);
            o[dt] = __builtin_amdgcn_mfma_f32_16x16x32_f16(pf[1], vf[dt][1], o[dt], 0, 0, 0);
        }
    }

    // ---- epilogue: normalize by l and store fp32 ----
    float* Ob = Og + ((size_t)b * kSQ + qb) * kD;
#pragma unroll
    for (int r = 0; r < 4; ++r) {
        const float linv = 1.0f / l_i[r];
        const int row = w * 16 + quad * 4 + r;
#pragma unroll
        for (int dt = 0; dt < 4; ++dt)
            Ob[(size_t)row * kD + dt * 16 + l16] = o[dt][r] * linv;
    }
}

extern "C" void kernel_launch(void* const* d_in, const int* in_sizes, int n_in,
                              void* d_out, int out_size, void* d_ws, size_t ws_size,
                              hipStream_t stream) {
    const float* Q    = (const float*)d_in[0];
    const float* K    = (const float*)d_in[1];
    const float* V    = (const float*)d_in[2];
    // d_in[3] = dropout p (static 0) -> unused
    const float* sdiv = (const float*)d_in[4];
    float* O = (float*)d_out;

    dim3 grid(kSQ / BQ, kB);
    fattn_kernel<<<grid, dim3(256), 0, stream>>>(Q, K, V, sdiv, O);
}

// Round 4
// 160.836 us; speedup vs baseline: 1.6031x; 1.6031x over previous
//
#include <hip/hip_runtime.h>

// Flash attention forward, fp32 in/out, fp16 MFMA compute.
// B=8, SQ=SK=4096, D=64. scores = (Q/x5) K^T ; softmax ; O = P V.
// R4: S^T formulation (S^T = K Q^T, O^T = V^T P^T) -> softmax needs only 2
// shuffles, scalar m/l/alpha per lane, b64 P-writes. Single-barrier
// register-prefetch double-buffered K/V staging. V staged transposed with
// key-pair b32 packing + xor-16 swizzle (8-way -> ~4-way conflicts).

typedef _Float16 f16x8 __attribute__((ext_vector_type(8)));
typedef __fp16   h16x2 __attribute__((ext_vector_type(2)));   // cvt_pkrtz return type
typedef float    f32x4 __attribute__((ext_vector_type(4)));

constexpr int kB  = 8;
constexpr int kSQ = 4096;
constexpr int kSK = 4096;
constexpr int kD  = 64;
constexpr int BQ  = 64;         // Q rows per block (4 waves x 16 rows)
constexpr int BK  = 64;         // keys per iteration
constexpr int LDK = kD + 8;     // 72 halves -> row stride 144 B (16B-aligned)
constexpr int LDV = BK + 8;     // 72
constexpr int LDP = BK + 8;     // 72

__global__ __launch_bounds__(256, 2)
void fattn_kernel(const float* __restrict__ Qg,
                  const float* __restrict__ Kg,
                  const float* __restrict__ Vg,
                  const float* __restrict__ sdiv,
                  float* __restrict__ Og)
{
    __shared__ __align__(16) _Float16 sK[2][BK][LDK];   // [buf][key][feat]
    __shared__ __align__(16) _Float16 sV[2][kD][LDV];   // [buf][feat][key^swz]
    __shared__ __align__(16) _Float16 sP[4][16][LDP];   // per-wave P: [qrow][key]

    const int tid  = threadIdx.x;
    const int w    = tid >> 6;
    const int lane = tid & 63;
    const int l16  = lane & 15;
    const int quad = lane >> 4;
    const int swz  = ((l16 >> 3) & 1) * 16;   // V key-swizzle for this lane's reads

    const int b  = blockIdx.y;
    const int qb = blockIdx.x * BQ;

    const float inv_scale = 1.0f / sdiv[0];

    const float* Qb = Qg + ((size_t)b * kSQ + qb) * kD;
    const float* Kb = Kg + (size_t)b * kSK * kD;
    const float* Vb = Vg + (size_t)b * kSK * kD;

    // ---- Q fragments: lane holds Q[row = w*16+l16][feat = ks*32+quad*8 ..+7]
    // (serves as B-frag of Q^T: n = qrow = l16, k = feat)
    f16x8 qf[2];
    {
        const float* qrow = Qb + (size_t)(w * 16 + l16) * kD;
#pragma unroll
        for (int ks = 0; ks < 2; ++ks) {
            const float4 a = *(const float4*)(qrow + ks * 32 + quad * 8);
            const float4 c = *(const float4*)(qrow + ks * 32 + quad * 8 + 4);
            h16x2 p0 = __builtin_amdgcn_cvt_pkrtz(a.x * inv_scale, a.y * inv_scale);
            h16x2 p1 = __builtin_amdgcn_cvt_pkrtz(a.z * inv_scale, a.w * inv_scale);
            h16x2 p2 = __builtin_amdgcn_cvt_pkrtz(c.x * inv_scale, c.y * inv_scale);
            h16x2 p3 = __builtin_amdgcn_cvt_pkrtz(c.z * inv_scale, c.w * inv_scale);
            f16x8 f;
            f[0] = (_Float16)p0[0]; f[1] = (_Float16)p0[1];
            f[2] = (_Float16)p1[0]; f[3] = (_Float16)p1[1];
            f[4] = (_Float16)p2[0]; f[5] = (_Float16)p2[1];
            f[6] = (_Float16)p3[0]; f[7] = (_Float16)p3[1];
            qf[ks] = f;
        }
    }

    // ---- staging registers (double-buffer prefetch) ----
    // i in {0,1}: idx = i*256+tid covers 32 key-pairs x 16 feat-quads
    float4 rk0[2], rk1[2], rv0[2], rv1[2];
    const int kp0 = 2 * ((0 * 256 + tid) >> 4), cb0 = ((0 * 256 + tid) & 15) * 4;
    const int kp1 = 2 * ((1 * 256 + tid) >> 4), cb1 = ((1 * 256 + tid) & 15) * 4;

    auto load_tile = [&](int kt) {
        const float* Kt = Kb + (size_t)kt * BK * kD;
        const float* Vt = Vb + (size_t)kt * BK * kD;
        rk0[0] = *(const float4*)(Kt + (kp0 + 0) * kD + cb0);
        rk1[0] = *(const float4*)(Kt + (kp0 + 1) * kD + cb0);
        rv0[0] = *(const float4*)(Vt + (kp0 + 0) * kD + cb0);
        rv1[0] = *(const float4*)(Vt + (kp0 + 1) * kD + cb0);
        rk0[1] = *(const float4*)(Kt + (kp1 + 0) * kD + cb1);
        rk1[1] = *(const float4*)(Kt + (kp1 + 1) * kD + cb1);
        rv0[1] = *(const float4*)(Vt + (kp1 + 0) * kD + cb1);
        rv1[1] = *(const float4*)(Vt + (kp1 + 1) * kD + cb1);
    };

    auto write_tile = [&](int buf) {
#pragma unroll
        for (int i = 0; i < 2; ++i) {
            const int kp = (i == 0) ? kp0 : kp1;
            const int cb = (i == 0) ? cb0 : cb1;
            const float4 k0 = (i == 0) ? rk0[0] : rk0[1];
            const float4 k1 = (i == 0) ? rk1[0] : rk1[1];
            const float4 v0 = (i == 0) ? rv0[0] : rv0[1];
            const float4 v1 = (i == 0) ? rv1[0] : rv1[1];
            // K rows: b64 contiguous writes
            h16x2* d0 = (h16x2*)&sK[buf][kp + 0][cb];
            d0[0] = __builtin_amdgcn_cvt_pkrtz(k0.x, k0.y);
            d0[1] = __builtin_amdgcn_cvt_pkrtz(k0.z, k0.w);
            h16x2* d1 = (h16x2*)&sK[buf][kp + 1][cb];
            d1[0] = __builtin_amdgcn_cvt_pkrtz(k1.x, k1.y);
            d1[1] = __builtin_amdgcn_cvt_pkrtz(k1.z, k1.w);
            // V transposed: pack key-pair per feat, b32 writes, xor-16 swizzle
            const float vx0[4] = {v0.x, v0.y, v0.z, v0.w};
            const float vx1[4] = {v1.x, v1.y, v1.z, v1.w};
#pragma unroll
            for (int j = 0; j < 4; ++j) {
                const int f = cb + j;
                const int sw = ((f >> 3) & 1) * 16;
                *(h16x2*)&sV[buf][f][kp ^ sw] =
                    __builtin_amdgcn_cvt_pkrtz(vx0[j], vx1[j]);
            }
        }
    };

    // ---- online-softmax state (scalar per lane: Q-row = l16) ----
    f32x4 o[4];                 // O^T accumulator: col = qrow = l16, row = feat
    float m_i = -1e30f, l_i = 0.0f;
#pragma unroll
    for (int dt = 0; dt < 4; ++dt)
#pragma unroll
        for (int r = 0; r < 4; ++r) o[dt][r] = 0.0f;

    // ---- prologue: stage tile 0 ----
    load_tile(0);
    write_tile(0);
    __syncthreads();

    const int nIter = kSK / BK;
    for (int kt = 0; kt < nIter; ++kt) {
        const int buf = kt & 1;
        const bool more = (kt + 1 < nIter);
        if (more) load_tile(kt + 1);     // global loads in flight during compute

        // ---- S^T = K Q^T : A = K[key][feat], B = Q^T[feat][qrow] ----
        // C-layout: col = l16 = qrow, row = key = nt*16 + quad*4 + r
        f32x4 s[4];
#pragma unroll
        for (int nt = 0; nt < 4; ++nt) {
            const f16x8 kf0 = *(const f16x8*)&sK[buf][nt * 16 + l16][quad * 8];
            const f16x8 kf1 = *(const f16x8*)&sK[buf][nt * 16 + l16][32 + quad * 8];
            f32x4 acc;
#pragma unroll
            for (int r = 0; r < 4; ++r) acc[r] = 0.0f;
            acc = __builtin_amdgcn_mfma_f32_16x16x32_f16(kf0, qf[0], acc, 0, 0, 0);
            acc = __builtin_amdgcn_mfma_f32_16x16x32_f16(kf1, qf[1], acc, 0, 0, 0);
            s[nt] = acc;
        }

        // ---- online softmax: lane owns 16 keys of Q-row l16 ----
        float rm = s[0][0];
#pragma unroll
        for (int nt = 0; nt < 4; ++nt)
#pragma unroll
            for (int r = 0; r < 4; ++r) rm = fmaxf(rm, s[nt][r]);
        rm = fmaxf(rm, __shfl_xor(rm, 16, 64));
        rm = fmaxf(rm, __shfl_xor(rm, 32, 64));
        const float mnew = fmaxf(m_i, rm);
        const float alpha = __expf(m_i - mnew);
        m_i = mnew;
        float rs = 0.0f;
#pragma unroll
        for (int nt = 0; nt < 4; ++nt)
#pragma unroll
            for (int r = 0; r < 4; ++r) {
                const float p = __expf(s[nt][r] - mnew);
                s[nt][r] = p;
                rs += p;
            }
        rs += __shfl_xor(rs, 16, 64);
        rs += __shfl_xor(rs, 32, 64);
        l_i = l_i * alpha + rs;
#pragma unroll
        for (int dt = 0; dt < 4; ++dt)
#pragma unroll
            for (int r = 0; r < 4; ++r) o[dt][r] *= alpha;

        // ---- P -> LDS: [qrow = l16][key], lane writes 4 consecutive keys/tile
#pragma unroll
        for (int nt = 0; nt < 4; ++nt) {
            h16x2* d = (h16x2*)&sP[w][l16][nt * 16 + quad * 4];
            d[0] = __builtin_amdgcn_cvt_pkrtz(s[nt][0], s[nt][1]);
            d[1] = __builtin_amdgcn_cvt_pkrtz(s[nt][2], s[nt][3]);
        }

        // ---- O^T += V^T P^T : A = V^T[feat][key], B = P^T[key][qrow] ----
        const f16x8 pf0 = *(const f16x8*)&sP[w][l16][quad * 8];
        const f16x8 pf1 = *(const f16x8*)&sP[w][l16][32 + quad * 8];
#pragma unroll
        for (int dt = 0; dt < 4; ++dt) {
            const f16x8 vf0 = *(const f16x8*)&sV[buf][dt * 16 + l16][(quad * 8) ^ swz];
            const f16x8 vf1 = *(const f16x8*)&sV[buf][dt * 16 + l16][(32 + quad * 8) ^ swz];
            o[dt] = __builtin_amdgcn_mfma_f32_16x16x32_f16(vf0, pf0, o[dt], 0, 0, 0);
            o[dt] = __builtin_amdgcn_mfma_f32_16x16x32_f16(vf1, pf1, o[dt], 0, 0, 0);
        }

        if (more) write_tile(buf ^ 1);   // loads drained here, hidden by compute
        __syncthreads();
    }

    // ---- epilogue: O^T -> O, normalize by l, float4 stores ----
    float* Ob = Og + ((size_t)b * kSQ + qb) * kD;
    const int qrow = w * 16 + l16;
    const float linv = 1.0f / l_i;
#pragma unroll
    for (int dt = 0; dt < 4; ++dt) {
        float4 st4;
        st4.x = o[dt][0] * linv;
        st4.y = o[dt][1] * linv;
        st4.z = o[dt][2] * linv;
        st4.w = o[dt][3] * linv;
        *(float4*)&Ob[(size_t)qrow * kD + dt * 16 + quad * 4] = st4;
    }
}

extern "C" void kernel_launch(void* const* d_in, const int* in_sizes, int n_in,
                              void* d_out, int out_size, void* d_ws, size_t ws_size,
                              hipStream_t stream) {
    const float* Q    = (const float*)d_in[0];
    const float* K    = (const float*)d_in[1];
    const float* V    = (const float*)d_in[2];
    // d_in[3] = dropout p (static 0) -> unused
    const float* sdiv = (const float*)d_in[4];
    float* O = (float*)d_out;

    dim3 grid(kSQ / BQ, kB);
    fattn_kernel<<<grid, dim3(256), 0, stream>>>(Q, K, V, sdiv, O);
}

// Round 5
// 149.138 us; speedup vs baseline: 1.7288x; 1.0784x over previous
//
#include <hip/hip_runtime.h>

// Flash attention forward, fp32 in/out, fp16 MFMA compute.
// B=8, SQ=SK=4096, D=64. scores = (Q/x5) K^T ; softmax ; O = P V.
// R5: LDS-pipe attack. R4 counters: LDS pipe ~94% busy, 670 cyc/block-iter of
// bank-conflict stall from V-transpose b32 staging writes (8-way). Fixes:
//  - V staging: thread owns 4-key x 4-feat cell -> one b64 write per feat,
//    4-key-block XOR swizzle (kq ^ (fq&14)) spreads banks; bit0 of the block
//    index untouched so 8-key read groups stay contiguous & in-order (b128).
//  - K and P LDS writes merged into single b64 stores (conflict-free pattern).
// Structure otherwise identical to R4 (S^T form, register-prefetch dbuf).

typedef _Float16 f16x8 __attribute__((ext_vector_type(8)));
typedef _Float16 f16x4 __attribute__((ext_vector_type(4)));
typedef __fp16   h16x2 __attribute__((ext_vector_type(2)));   // cvt_pkrtz return type
typedef float    f32x4 __attribute__((ext_vector_type(4)));

constexpr int kB  = 8;
constexpr int kSQ = 4096;
constexpr int kSK = 4096;
constexpr int kD  = 64;
constexpr int BQ  = 64;         // Q rows per block (4 waves x 16 rows)
constexpr int BK  = 64;         // keys per iteration
constexpr int LDK = kD + 8;     // 72 halves -> row stride 144 B
constexpr int LDV = BK + 8;     // 72
constexpr int LDP = BK + 8;     // 72

static __device__ __forceinline__ f16x4 pack4(float a, float b, float c, float d) {
    h16x2 p0 = __builtin_amdgcn_cvt_pkrtz(a, b);
    h16x2 p1 = __builtin_amdgcn_cvt_pkrtz(c, d);
    f16x4 r;
    r[0] = (_Float16)p0[0]; r[1] = (_Float16)p0[1];
    r[2] = (_Float16)p1[0]; r[3] = (_Float16)p1[1];
    return r;
}

__global__ __launch_bounds__(256, 2)
void fattn_kernel(const float* __restrict__ Qg,
                  const float* __restrict__ Kg,
                  const float* __restrict__ Vg,
                  const float* __restrict__ sdiv,
                  float* __restrict__ Og)
{
    __shared__ __align__(16) _Float16 sK[2][BK][LDK];   // [buf][key][feat]
    __shared__ __align__(16) _Float16 sV[2][kD][LDV];   // [buf][feat][key, 4-blk swz]
    __shared__ __align__(16) _Float16 sP[4][16][LDP];   // per-wave P: [qrow][key]

    const int tid  = threadIdx.x;
    const int w    = tid >> 6;
    const int lane = tid & 63;
    const int l16  = lane & 15;
    const int quad = lane >> 4;

    const int b  = blockIdx.y;
    const int qb = blockIdx.x * BQ;

    const float inv_scale = 1.0f / sdiv[0];

    const float* Qb = Qg + ((size_t)b * kSQ + qb) * kD;
    const float* Kb = Kg + (size_t)b * kSK * kD;
    const float* Vb = Vg + (size_t)b * kSK * kD;

    // ---- Q fragments: lane holds Q[row = w*16+l16][feat = ks*32+quad*8 ..+7]
    f16x8 qf[2];
    {
        const float* qrow = Qb + (size_t)(w * 16 + l16) * kD;
#pragma unroll
        for (int ks = 0; ks < 2; ++ks) {
            const float4 a = *(const float4*)(qrow + ks * 32 + quad * 8);
            const float4 c = *(const float4*)(qrow + ks * 32 + quad * 8 + 4);
            f16x4 lo = pack4(a.x * inv_scale, a.y * inv_scale, a.z * inv_scale, a.w * inv_scale);
            f16x4 hi = pack4(c.x * inv_scale, c.y * inv_scale, c.z * inv_scale, c.w * inv_scale);
            f16x8 f;
            f[0] = lo[0]; f[1] = lo[1]; f[2] = lo[2]; f[3] = lo[3];
            f[4] = hi[0]; f[5] = hi[1]; f[6] = hi[2]; f[7] = hi[3];
            qf[ks] = f;
        }
    }

    // ---- staging maps ----
    // K: two sets, thread -> (key-pair, feat-quad); coalesced float4 loads.
    const int kp0 = 2 * ((0 * 256 + tid) >> 4), cb0 = ((0 * 256 + tid) & 15) * 4;
    const int kp1 = 2 * ((1 * 256 + tid) >> 4), cb1 = ((1 * 256 + tid) & 15) * 4;
    // V: thread -> (key-quad kq, feat-quad fq); 16x16 cells = 256 threads.
    const int kq  = tid >> 4;          // keys 4kq..4kq+3
    const int fq  = tid & 15;          // feats 4fq..4fq+3
    const int kqs = (kq ^ (fq & 14)) * 4;  // swizzled key base for writes

    float4 rk[2][2];                   // [set][row-of-pair]
    float4 rv[4];                      // 4 key rows x this thread's 4 feats

    auto load_tile = [&](int kt) {
        const float* Kt = Kb + (size_t)kt * BK * kD;
        const float* Vt = Vb + (size_t)kt * BK * kD;
        rk[0][0] = *(const float4*)(Kt + (kp0 + 0) * kD + cb0);
        rk[0][1] = *(const float4*)(Kt + (kp0 + 1) * kD + cb0);
        rk[1][0] = *(const float4*)(Kt + (kp1 + 0) * kD + cb1);
        rk[1][1] = *(const float4*)(Kt + (kp1 + 1) * kD + cb1);
#pragma unroll
        for (int r = 0; r < 4; ++r)
            rv[r] = *(const float4*)(Vt + (4 * kq + r) * kD + 4 * fq);
    };

    auto write_tile = [&](int buf) {
        // K rows: one b64 store per row (conflict-free: dword = kp*36 + 2*l16)
        *(f16x4*)&sK[buf][kp0 + 0][cb0] = pack4(rk[0][0].x, rk[0][0].y, rk[0][0].z, rk[0][0].w);
        *(f16x4*)&sK[buf][kp0 + 1][cb0] = pack4(rk[0][1].x, rk[0][1].y, rk[0][1].z, rk[0][1].w);
        *(f16x4*)&sK[buf][kp1 + 0][cb1] = pack4(rk[1][0].x, rk[1][0].y, rk[1][0].z, rk[1][0].w);
        *(f16x4*)&sK[buf][kp1 + 1][cb1] = pack4(rk[1][1].x, rk[1][1].y, rk[1][1].z, rk[1][1].w);
        // V transposed: one b64 (4 keys) per feat, swizzled key-block.
        const float vx[4][4] = {
            {rv[0].x, rv[0].y, rv[0].z, rv[0].w},
            {rv[1].x, rv[1].y, rv[1].z, rv[1].w},
            {rv[2].x, rv[2].y, rv[2].z, rv[2].w},
            {rv[3].x, rv[3].y, rv[3].z, rv[3].w}};
#pragma unroll
        for (int j = 0; j < 4; ++j)
            *(f16x4*)&sV[buf][4 * fq + j][kqs] =
                pack4(vx[0][j], vx[1][j], vx[2][j], vx[3][j]);
    };

    // ---- online-softmax state (scalar per lane: Q-row = l16) ----
    f32x4 o[4];                 // O^T accumulator: col = qrow = l16, row = feat
    float m_i = -1e30f, l_i = 0.0f;
#pragma unroll
    for (int dt = 0; dt < 4; ++dt)
#pragma unroll
        for (int r = 0; r < 4; ++r) o[dt][r] = 0.0f;

    // ---- prologue: stage tile 0 ----
    load_tile(0);
    write_tile(0);
    __syncthreads();

    const int nIter = kSK / BK;
    for (int kt = 0; kt < nIter; ++kt) {
        const int buf = kt & 1;
        const bool more = (kt + 1 < nIter);
        if (more) load_tile(kt + 1);     // global loads in flight during compute

        // ---- S^T = K Q^T : A = K[key][feat], B = Q^T[feat][qrow] ----
        // C-layout: col = l16 = qrow, row = key = nt*16 + quad*4 + r
        f32x4 s[4];
#pragma unroll
        for (int nt = 0; nt < 4; ++nt) {
            const f16x8 kf0 = *(const f16x8*)&sK[buf][nt * 16 + l16][quad * 8];
            const f16x8 kf1 = *(const f16x8*)&sK[buf][nt * 16 + l16][32 + quad * 8];
            f32x4 acc;
#pragma unroll
            for (int r = 0; r < 4; ++r) acc[r] = 0.0f;
            acc = __builtin_amdgcn_mfma_f32_16x16x32_f16(kf0, qf[0], acc, 0, 0, 0);
            acc = __builtin_amdgcn_mfma_f32_16x16x32_f16(kf1, qf[1], acc, 0, 0, 0);
            s[nt] = acc;
        }

        // ---- online softmax: lane owns 16 keys of Q-row l16 ----
        float rm = s[0][0];
#pragma unroll
        for (int nt = 0; nt < 4; ++nt)
#pragma unroll
            for (int r = 0; r < 4; ++r) rm = fmaxf(rm, s[nt][r]);
        rm = fmaxf(rm, __shfl_xor(rm, 16, 64));
        rm = fmaxf(rm, __shfl_xor(rm, 32, 64));
        const float mnew = fmaxf(m_i, rm);
        const float alpha = __expf(m_i - mnew);
        m_i = mnew;
        float rs = 0.0f;
#pragma unroll
        for (int nt = 0; nt < 4; ++nt)
#pragma unroll
            for (int r = 0; r < 4; ++r) {
                const float p = __expf(s[nt][r] - mnew);
                s[nt][r] = p;
                rs += p;
            }
        rs += __shfl_xor(rs, 16, 64);
        rs += __shfl_xor(rs, 32, 64);
        l_i = l_i * alpha + rs;
#pragma unroll
        for (int dt = 0; dt < 4; ++dt)
#pragma unroll
            for (int r = 0; r < 4; ++r) o[dt][r] *= alpha;

        // ---- P -> LDS: [qrow = l16][key], one b64 per tile (4 consecutive keys)
#pragma unroll
        for (int nt = 0; nt < 4; ++nt)
            *(f16x4*)&sP[w][l16][nt * 16 + quad * 4] =
                pack4(s[nt][0], s[nt][1], s[nt][2], s[nt][3]);

        // ---- O^T += V^T P^T : A = V^T[feat][key], B = P^T[key][qrow] ----
        const f16x8 pf0 = *(const f16x8*)&sP[w][l16][quad * 8];
        const f16x8 pf1 = *(const f16x8*)&sP[w][l16][32 + quad * 8];
#pragma unroll
        for (int dt = 0; dt < 4; ++dt) {
            const int f   = dt * 16 + l16;
            const int sw  = (f >> 2) & 14;
            const f16x8 vf0 = *(const f16x8*)&sV[buf][f][((2 * quad) ^ sw) * 4];
            const f16x8 vf1 = *(const f16x8*)&sV[buf][f][((8 + 2 * quad) ^ sw) * 4];
            o[dt] = __builtin_amdgcn_mfma_f32_16x16x32_f16(vf0, pf0, o[dt], 0, 0, 0);
            o[dt] = __builtin_amdgcn_mfma_f32_16x16x32_f16(vf1, pf1, o[dt], 0, 0, 0);
        }

        if (more) write_tile(buf ^ 1);   // loads drained here, hidden by compute
        __syncthreads();
    }

    // ---- epilogue: O^T -> O, normalize by l, float4 stores ----
    float* Ob = Og + ((size_t)b * kSQ + qb) * kD;
    const int qrow = w * 16 + l16;
    const float linv = 1.0f / l_i;
#pragma unroll
    for (int dt = 0; dt < 4; ++dt) {
        float4 st4;
        st4.x = o[dt][0] * linv;
        st4.y = o[dt][1] * linv;
        st4.z = o[dt][2] * linv;
        st4.w = o[dt][3] * linv;
        *(float4*)&Ob[(size_t)qrow * kD + dt * 16 + quad * 4] = st4;
    }
}

extern "C" void kernel_launch(void* const* d_in, const int* in_sizes, int n_in,
                              void* d_out, int out_size, void* d_ws, size_t ws_size,
                              hipStream_t stream) {
    const float* Q    = (const float*)d_in[0];
    const float* K    = (const float*)d_in[1];
    const float* V    = (const float*)d_in[2];
    // d_in[3] = dropout p (static 0) -> unused
    const float* sdiv = (const float*)d_in[4];
    float* O = (float*)d_out;

    dim3 grid(kSQ / BQ, kB);
    fattn_kernel<<<grid, dim3(256), 0, stream>>>(Q, K, V, sdiv, O);
}